// Round 6
// baseline (177.155 us; speedup 1.0000x reference)
//
#include <hip/hip_runtime.h>

#define NB 8
#define NN 128
#define ND 64
#define NE 3
#define NH 256
#define NOUT 64

typedef short bf16x8_t __attribute__((ext_vector_type(8)));
typedef float f32x4_t __attribute__((ext_vector_type(4)));

static __device__ __forceinline__ unsigned short f2bf(float f) {
    unsigned u = __float_as_uint(f);
    u += 0x7FFFu + ((u >> 16) & 1u);
    return (unsigned short)(u >> 16);
}
static __device__ __forceinline__ unsigned pk2bf(float a, float b) {
    return (unsigned)f2bf(a) | ((unsigned)f2bf(b) << 16);
}
static __device__ __forceinline__ float bflo(unsigned u) { return __uint_as_float(u << 16); }
static __device__ __forceinline__ float bfhi(unsigned u) { return __uint_as_float(u & 0xffff0000u); }

// ---------------- Kernel 0+1 merged: weight prep (blocks 0..287) + P/Q (blocks 288..479) ----------------
#define IT 16
__global__ __launch_bounds__(256) void prep_pq_kernel(
    const float* __restrict__ We2, const float* __restrict__ Wd1,
    const float* __restrict__ Wd2, const float* __restrict__ ns,
    const float* __restrict__ We1, const float* __restrict__ be1,
    unsigned short* __restrict__ We2t, float* __restrict__ Wd1t,
    float* __restrict__ Wd2t,
    unsigned short* __restrict__ P, unsigned short* __restrict__ Q)
{
    __shared__ float tile[32][33];
    __shared__ float ns_lds[IT][ND];
    const int t = threadIdx.x;
    const int blk = blockIdx.x;
    if (blk < 288) {
        const int tx = t & 31, ty = t >> 5;
        if (blk < 192) {
            const int e = blk >> 6, kt = (blk >> 3) & 7, nt = blk & 7;
            const float* src = We2 + ((size_t)e * NH + kt * 32) * NH + nt * 32;
#pragma unroll
            for (int s = 0; s < 4; s++) { const int k = ty + 8 * s; tile[k][tx] = src[(size_t)k * NH + tx]; }
            __syncthreads();
            unsigned short* dst = We2t + ((size_t)e * NH + nt * 32) * NH + kt * 32;
#pragma unroll
            for (int s = 0; s < 4; s++) { const int n = ty + 8 * s; dst[(size_t)n * NH + tx] = f2bf(tile[tx][n]); }
        } else if (blk < 272) {
            const int tt = blk - 192, kt = tt >> 3, nt = tt & 7;
            const float* src = Wd1 + ((size_t)kt * 32) * NH + nt * 32;
#pragma unroll
            for (int s = 0; s < 4; s++) { const int k = ty + 8 * s; tile[k][tx] = src[(size_t)k * NH + tx]; }
            __syncthreads();
            float* dst = Wd1t + ((size_t)(nt * 32)) * 320 + kt * 32;
#pragma unroll
            for (int s = 0; s < 4; s++) { const int n = ty + 8 * s; dst[(size_t)n * 320 + tx] = tile[tx][n]; }
        } else {
            const int tt = blk - 272, kt = tt >> 1, nt = tt & 1;
            const float* src = Wd2 + ((size_t)kt * 32) * NOUT + nt * 32;
#pragma unroll
            for (int s = 0; s < 4; s++) { const int k = ty + 8 * s; tile[k][tx] = src[(size_t)k * NOUT + tx]; }
            __syncthreads();
            float* dst = Wd2t + ((size_t)(nt * 32)) * NH + kt * 32;
#pragma unroll
            for (int s = 0; s < 4; s++) { const int n = ty + 8 * s; dst[(size_t)n * NH + tx] = tile[tx][n]; }
        }
        return;
    }
    // ---- P/Q part ----
    const int blk2 = blk - 288;
    const int itile = blk2 & 7;
    const int e = (blk2 >> 3) % NE;
    const int b = blk2 / (8 * NE);
    const int i0 = itile * IT;
    for (int x = t; x < IT * ND; x += 256)
        ns_lds[x / ND][x % ND] = ns[(size_t)(b * NN + i0 + x / ND) * ND + (x % ND)];
    __syncthreads();
    const int h = t;
    float accP[IT], accQ[IT];
    const float bias = be1[e * NH + h];
#pragma unroll
    for (int m = 0; m < IT; m++) { accP[m] = 0.f; accQ[m] = bias; }
    const float* W1 = We1 + (size_t)e * 2 * ND * NH + h;
    for (int d = 0; d < ND; d++) {
        const float w1 = W1[(size_t)d * NH];
        const float w2 = W1[(size_t)(ND + d) * NH];
#pragma unroll
        for (int m = 0; m < IT; m++) {
            accP[m] = fmaf(ns_lds[m][d], w1, accP[m]);
            accQ[m] = fmaf(ns_lds[m][d], w2, accQ[m]);
        }
    }
#pragma unroll
    for (int m = 0; m < IT; m++) {
        const size_t idx = ((size_t)((b * NE + e) * NN) + i0 + m) * NH + h;
        P[idx] = f2bf(accP[m]);
        Q[idx] = f2bf(accQ[m]);
    }
}

// ---------------- MFMA tile helper: NMF 16-row sub-tiles share each B-frag ----------------
template<int NMF>
static __device__ __forceinline__ void do_tile(
    const char* At, const unsigned short* Bt, int wave, int lane,
    int base, int ce, const float* bb, float* rsum)
{
    f32x4_t acc[NMF][4];
    const f32x4_t z4 = {0.f, 0.f, 0.f, 0.f};
#pragma unroll
    for (int mf = 0; mf < NMF; mf++)
#pragma unroll
        for (int nf = 0; nf < 4; nf++) acc[mf][nf] = z4;
#pragma unroll
    for (int kk = 0; kk < 8; kk++) {
        bf16x8_t af[NMF];
        const int koff = kk * 64 + (lane >> 4) * 16;
#pragma unroll
        for (int mf = 0; mf < NMF; mf++) {
            const int lr = mf * 16 + (lane & 15);
            af[mf] = *(const bf16x8_t*)(At + ((lr * 512 + koff) ^ ((lr & 7) << 4)));
        }
#pragma unroll
        for (int nf = 0; nf < 4; nf++) {
            const int n = wave * 64 + nf * 16 + (lane & 15);
            const bf16x8_t bfr = *(const bf16x8_t*)(Bt + (size_t)n * NH + kk * 32 + (lane >> 4) * 8);
#pragma unroll
            for (int mf = 0; mf < NMF; mf++)
                acc[mf][nf] = __builtin_amdgcn_mfma_f32_16x16x32_bf16(af[mf], bfr, acc[mf][nf], 0, 0, 0);
        }
    }
#pragma unroll
    for (int mf = 0; mf < NMF; mf++) {
#pragma unroll
        for (int r = 0; r < 4; r++) {
            const int g = base + mf * 16 + ((lane >> 4) << 2) + r;
            if (g < ce) {
#pragma unroll
                for (int nf = 0; nf < 4; nf++)
                    rsum[nf] += fmaxf(acc[mf][nf][r] + bb[nf], 0.f);
            }
        }
    }
}

// ---------------- Kernel 2: per (b, j) MFMA + aggregate + fused decoder ----------------
__global__ __launch_bounds__(256, 4) void edge_kernel(
    const float* __restrict__ ns,
    const float* __restrict__ edges,
    const unsigned short* __restrict__ Pbf,
    const unsigned short* __restrict__ Qbf,
    const unsigned short* __restrict__ We2t,
    const float* __restrict__ be2,
    const float* __restrict__ Wd1t,
    const float* __restrict__ bd1,
    const float* __restrict__ Wd2t,
    const float* __restrict__ bd2,
    float* __restrict__ out)
{
    const int b = blockIdx.x >> 7;
    const int j = blockIdx.x & 127;
    const int tid = threadIdx.x;
    const int lane = tid & 63;
    const int wave = tid >> 6;

    __shared__ __align__(16) char At[64 * 512];     // 64 rows x 256 bf16, swizzled (32 KB)
    __shared__ float qjs[NH];
    __shared__ int lists[NE][NN];
    __shared__ unsigned long long wm[2][NE];
    __shared__ int cnts[NE];
    __shared__ float aggr[NH];
    __shared__ float o1s[NH];
    __shared__ float nsr[ND];

    // ---- bucket build: 128 sources classified by waves 0-1 ----
    int ecls = -1;
    if (tid < 128) {
        const float4 ev = *(const float4*)(edges + ((size_t)(b * NN + tid) * NN + j) * 4);
        ecls = ev.y > 0.5f ? 0 : (ev.z > 0.5f ? 1 : (ev.w > 0.5f ? 2 : -1));
#pragma unroll
        for (int ee = 0; ee < NE; ee++) {
            unsigned long long m = __ballot(ecls == ee);
            if (lane == 0) wm[wave][ee] = m;
        }
    }
    __syncthreads();
    if (tid < 128 && ecls >= 0) {
        const unsigned long long lower = (1ull << lane) - 1ull;
        int pos = __popcll(wm[wave][ecls] & lower);
        if (wave == 1) pos += __popcll(wm[0][ecls]);
        lists[ecls][pos] = tid;
    }
    if (tid < NE) cnts[tid] = __popcll(wm[0][tid]) + __popcll(wm[1][tid]);
    if (tid >= 128 && tid < 192) nsr[tid - 128] = ns[((size_t)b * NN + j) * ND + (tid - 128)];
    __syncthreads();

    float rsum[4] = {0.f, 0.f, 0.f, 0.f};

    for (int e = 0; e < NE; e++) {
        const int ce = cnts[e];
        if (ce == 0) continue;
        {   // qjs: bf16 -> f32 (one element per thread)
            qjs[tid] = __uint_as_float((unsigned)Qbf[(((size_t)b * NE + e) * NN + j) * NH + tid] << 16);
        }
        float bb[4];
#pragma unroll
        for (int nf = 0; nf < 4; nf++)
            bb[nf] = be2[e * NH + wave * 64 + nf * 16 + (lane & 15)];
        const unsigned short* Bt = We2t + (size_t)e * NH * NH;
        const unsigned short* Pb = Pbf + (size_t)(b * NE + e) * NN * NH;

        for (int base = 0; base < ce; base += 64) {
            __syncthreads();   // prev tile's readers done + qjs visible
            {   // ---- stage packed rows: relu(P_i + Q_j) -> bf16, swizzled; 4 thr/row ----
                const int r = tid >> 2, q = tid & 3;
                const int rows = ce - base < 64 ? ce - base : 64;
                const int pad16 = (rows + 15) & ~15;
                char* wb = At + r * 512;
                const int swz = (r & 7) << 4;
                if (r < rows) {
                    const int i = lists[e][base + r];
                    const unsigned short* Pr = Pb + (size_t)i * NH + q * 64;
                    const float* qr = &qjs[q * 64];
#pragma unroll
                    for (int x = 0; x < 8; x++) {
                        const uint4 pv = *(const uint4*)(Pr + x * 8);
                        const float4 q0 = *(const float4*)(qr + x * 8);
                        const float4 q1 = *(const float4*)(qr + x * 8 + 4);
                        const float f0 = fmaxf(bflo(pv.x) + q0.x, 0.f);
                        const float f1 = fmaxf(bfhi(pv.x) + q0.y, 0.f);
                        const float f2 = fmaxf(bflo(pv.y) + q0.z, 0.f);
                        const float f3 = fmaxf(bfhi(pv.y) + q0.w, 0.f);
                        const float f4 = fmaxf(bflo(pv.z) + q1.x, 0.f);
                        const float f5 = fmaxf(bfhi(pv.z) + q1.y, 0.f);
                        const float f6 = fmaxf(bflo(pv.w) + q1.z, 0.f);
                        const float f7 = fmaxf(bfhi(pv.w) + q1.w, 0.f);
                        uint4 pk;
                        pk.x = pk2bf(f0, f1); pk.y = pk2bf(f2, f3);
                        pk.z = pk2bf(f4, f5); pk.w = pk2bf(f6, f7);
                        *(uint4*)(wb + ((q * 128 + x * 16) ^ swz)) = pk;
                    }
                } else if (r < pad16) {
                    const uint4 z = {0u, 0u, 0u, 0u};
#pragma unroll
                    for (int x = 0; x < 8; x++)
                        *(uint4*)(wb + ((q * 128 + x * 16) ^ swz)) = z;
                }
            }
            __syncthreads();
            const int rows = ce - base < 64 ? ce - base : 64;
            const int nmf = (rows + 15) >> 4;
            switch (nmf) {   // block-uniform
                case 1: do_tile<1>(At, Bt, wave, lane, base, ce, bb, rsum); break;
                case 2: do_tile<2>(At, Bt, wave, lane, base, ce, bb, rsum); break;
                case 3: do_tile<3>(At, Bt, wave, lane, base, ce, bb, rsum); break;
                default: do_tile<4>(At, Bt, wave, lane, base, ce, bb, rsum); break;
            }
        }
    }

    // ---- reduce column sums over the 4 row-groups ----
#pragma unroll
    for (int nf = 0; nf < 4; nf++) {
        float v = rsum[nf];
        v += __shfl_xor(v, 16, 64);
        v += __shfl_xor(v, 32, 64);
        rsum[nf] = v;
    }
    if ((lane >> 4) == 0) {
#pragma unroll
        for (int nf = 0; nf < 4; nf++)
            aggr[wave * 64 + nf * 16 + lane] = rsum[nf];
    }
    __syncthreads();

    // ---- decoder layer 1: [ns(64), aggr(256)] -> relu(.Wd1 + bd1)(256) ----
    {
        const int col = tid;
        float a0 = bd1[col];
        const float* W = Wd1t + (size_t)col * 320;
#pragma unroll 4
        for (int cb = 0; cb < 16; cb++) {
            const float4 w = *(const float4*)(W + cb * 4);
            const float4 x0 = *(const float4*)(&nsr[cb * 4]);
            a0 = fmaf(w.x, x0.x, fmaf(w.y, x0.y, fmaf(w.z, x0.z, fmaf(w.w, x0.w, a0))));
        }
#pragma unroll 4
        for (int cb = 0; cb < 64; cb++) {
            const float4 w = *(const float4*)(W + 64 + cb * 4);
            const float4 x0 = *(const float4*)(&aggr[cb * 4]);
            a0 = fmaf(w.x, x0.x, fmaf(w.y, x0.y, fmaf(w.z, x0.z, fmaf(w.w, x0.w, a0))));
        }
        o1s[col] = fmaxf(a0, 0.f);
    }
    __syncthreads();
    // ---- decoder layer 2: (256) -> relu(.Wd2 + bd2)(64) ----
    if (tid < NOUT) {
        float a2 = bd2[tid];
        const float* W2 = Wd2t + (size_t)tid * NH;
#pragma unroll 4
        for (int hb = 0; hb < 64; hb++) {
            const float4 w = *(const float4*)(W2 + hb * 4);
            const float4 x = *(const float4*)(&o1s[hb * 4]);
            a2 = fmaf(w.x, x.x, fmaf(w.y, x.y, fmaf(w.z, x.z, fmaf(w.w, x.w, a2))));
        }
        out[((size_t)b * NN + j) * NOUT + tid] = fmaxf(a2, 0.f);
    }
}

extern "C" void kernel_launch(void* const* d_in, const int* in_sizes, int n_in,
                              void* d_out, int out_size, void* d_ws, size_t ws_size,
                              hipStream_t stream)
{
    const float* ns    = (const float*)d_in[0];
    const float* edges = (const float*)d_in[1];
    const float* We1   = (const float*)d_in[2];
    const float* be1   = (const float*)d_in[3];
    const float* We2   = (const float*)d_in[4];
    const float* be2   = (const float*)d_in[5];
    const float* Wd1   = (const float*)d_in[6];
    const float* bd1   = (const float*)d_in[7];
    const float* Wd2   = (const float*)d_in[8];
    const float* bd2   = (const float*)d_in[9];
    float* outp = (float*)d_out;

    unsigned short* Pbf  = (unsigned short*)d_ws;
    unsigned short* Qbf  = Pbf + (size_t)NB * NE * NN * NH;
    unsigned short* We2t = Qbf + (size_t)NB * NE * NN * NH;
    float* Wd1t = (float*)(We2t + (size_t)NE * NH * NH);
    float* Wd2t = Wd1t + 256 * 320;

    hipLaunchKernelGGL(prep_pq_kernel, dim3(480), dim3(256), 0, stream,
                       We2, Wd1, Wd2, ns, We1, be1, We2t, Wd1t, Wd2t, Pbf, Qbf);
    hipLaunchKernelGGL(edge_kernel, dim3(NB * NN), dim3(256), 0, stream,
                       ns, edges, Pbf, Qbf, We2t, be2, Wd1t, bd1, Wd2t, bd2, outp);
}

// Round 7
// 155.640 us; speedup vs baseline: 1.1382x; 1.1382x over previous
//
#include <hip/hip_runtime.h>

#define NB 8
#define NN 128
#define ND 64
#define NE 3
#define NH 256
#define NOUT 64

typedef short bf16x8_t __attribute__((ext_vector_type(8)));
typedef float f32x4_t __attribute__((ext_vector_type(4)));

static __device__ __forceinline__ unsigned short f2bf(float f) {
    unsigned u = __float_as_uint(f);
    u += 0x7FFFu + ((u >> 16) & 1u);
    return (unsigned short)(u >> 16);
}
static __device__ __forceinline__ unsigned pk2bf(float a, float b) {
    return (unsigned)f2bf(a) | ((unsigned)f2bf(b) << 16);
}
static __device__ __forceinline__ float bflo(unsigned u) { return __uint_as_float(u << 16); }
static __device__ __forceinline__ float bfhi(unsigned u) { return __uint_as_float(u & 0xffff0000u); }

// ---------------- Kernel 0+1 merged: weight prep (blocks 0..287) + P/Q (blocks 288..479) ----------------
#define IT 16
__global__ __launch_bounds__(256) void prep_pq_kernel(
    const float* __restrict__ We2, const float* __restrict__ Wd1,
    const float* __restrict__ Wd2, const float* __restrict__ ns,
    const float* __restrict__ We1, const float* __restrict__ be1,
    unsigned short* __restrict__ We2t, float* __restrict__ Wd1t,
    float* __restrict__ Wd2t,
    unsigned short* __restrict__ P, unsigned short* __restrict__ Q)
{
    __shared__ float tile[32][33];
    __shared__ float ns_lds[IT][ND];
    const int t = threadIdx.x;
    const int blk = blockIdx.x;
    if (blk < 288) {
        const int tx = t & 31, ty = t >> 5;
        if (blk < 192) {
            const int e = blk >> 6, kt = (blk >> 3) & 7, nt = blk & 7;
            const float* src = We2 + ((size_t)e * NH + kt * 32) * NH + nt * 32;
#pragma unroll
            for (int s = 0; s < 4; s++) { const int k = ty + 8 * s; tile[k][tx] = src[(size_t)k * NH + tx]; }
            __syncthreads();
            unsigned short* dst = We2t + ((size_t)e * NH + nt * 32) * NH + kt * 32;
#pragma unroll
            for (int s = 0; s < 4; s++) { const int n = ty + 8 * s; dst[(size_t)n * NH + tx] = f2bf(tile[tx][n]); }
        } else if (blk < 272) {
            const int tt = blk - 192, kt = tt >> 3, nt = tt & 7;
            const float* src = Wd1 + ((size_t)kt * 32) * NH + nt * 32;
#pragma unroll
            for (int s = 0; s < 4; s++) { const int k = ty + 8 * s; tile[k][tx] = src[(size_t)k * NH + tx]; }
            __syncthreads();
            float* dst = Wd1t + ((size_t)(nt * 32)) * 320 + kt * 32;
#pragma unroll
            for (int s = 0; s < 4; s++) { const int n = ty + 8 * s; dst[(size_t)n * 320 + tx] = tile[tx][n]; }
        } else {
            const int tt = blk - 272, kt = tt >> 1, nt = tt & 1;
            const float* src = Wd2 + ((size_t)kt * 32) * NOUT + nt * 32;
#pragma unroll
            for (int s = 0; s < 4; s++) { const int k = ty + 8 * s; tile[k][tx] = src[(size_t)k * NOUT + tx]; }
            __syncthreads();
            float* dst = Wd2t + ((size_t)(nt * 32)) * NH + kt * 32;
#pragma unroll
            for (int s = 0; s < 4; s++) { const int n = ty + 8 * s; dst[(size_t)n * NH + tx] = tile[tx][n]; }
        }
        return;
    }
    // ---- P/Q part ----
    const int blk2 = blk - 288;
    const int itile = blk2 & 7;
    const int e = (blk2 >> 3) % NE;
    const int b = blk2 / (8 * NE);
    const int i0 = itile * IT;
    for (int x = t; x < IT * ND; x += 256)
        ns_lds[x / ND][x % ND] = ns[(size_t)(b * NN + i0 + x / ND) * ND + (x % ND)];
    __syncthreads();
    const int h = t;
    float accP[IT], accQ[IT];
    const float bias = be1[e * NH + h];
#pragma unroll
    for (int m = 0; m < IT; m++) { accP[m] = 0.f; accQ[m] = bias; }
    const float* W1 = We1 + (size_t)e * 2 * ND * NH + h;
    for (int d = 0; d < ND; d++) {
        const float w1 = W1[(size_t)d * NH];
        const float w2 = W1[(size_t)(ND + d) * NH];
#pragma unroll
        for (int m = 0; m < IT; m++) {
            accP[m] = fmaf(ns_lds[m][d], w1, accP[m]);
            accQ[m] = fmaf(ns_lds[m][d], w2, accQ[m]);
        }
    }
#pragma unroll
    for (int m = 0; m < IT; m++) {
        const size_t idx = ((size_t)((b * NE + e) * NN) + i0 + m) * NH + h;
        P[idx] = f2bf(accP[m]);
        Q[idx] = f2bf(accQ[m]);
    }
}

// ---------------- Kernel 2: per (b, j) MFMA + aggregate + fused decoder ----------------
// 32-row tiles, fixed 2 sub-tiles of 16 rows -> acc is only 32 VGPRs.
__global__ __launch_bounds__(256) void edge_kernel(
    const float* __restrict__ ns,
    const float* __restrict__ edges,
    const unsigned short* __restrict__ Pbf,
    const unsigned short* __restrict__ Qbf,
    const unsigned short* __restrict__ We2t,
    const float* __restrict__ be2,
    const float* __restrict__ Wd1t,
    const float* __restrict__ bd1,
    const float* __restrict__ Wd2t,
    const float* __restrict__ bd2,
    float* __restrict__ out)
{
    const int b = blockIdx.x >> 7;
    const int j = blockIdx.x & 127;
    const int tid = threadIdx.x;
    const int lane = tid & 63;
    const int wave = tid >> 6;

    __shared__ __align__(16) char At[32 * 512];     // 32 rows x 256 bf16, swizzled (16 KB)
    __shared__ float qjs[NH];
    __shared__ int lists[NE][NN];
    __shared__ unsigned long long wm[2][NE];
    __shared__ int cnts[NE];
    __shared__ float aggr[NH];
    __shared__ float o1s[NH];
    __shared__ float nsr[ND];

    // ---- bucket build: 128 sources classified by waves 0-1 ----
    int ecls = -1;
    if (tid < 128) {
        const float4 ev = *(const float4*)(edges + ((size_t)(b * NN + tid) * NN + j) * 4);
        ecls = ev.y > 0.5f ? 0 : (ev.z > 0.5f ? 1 : (ev.w > 0.5f ? 2 : -1));
#pragma unroll
        for (int ee = 0; ee < NE; ee++) {
            unsigned long long m = __ballot(ecls == ee);
            if (lane == 0) wm[wave][ee] = m;
        }
    }
    __syncthreads();
    if (tid < 128 && ecls >= 0) {
        const unsigned long long lower = (1ull << lane) - 1ull;
        int pos = __popcll(wm[wave][ecls] & lower);
        if (wave == 1) pos += __popcll(wm[0][ecls]);
        lists[ecls][pos] = tid;
    }
    if (tid < NE) cnts[tid] = __popcll(wm[0][tid]) + __popcll(wm[1][tid]);
    if (tid >= 128 && tid < 192) nsr[tid - 128] = ns[((size_t)b * NN + j) * ND + (tid - 128)];
    __syncthreads();

    float rsum[4] = {0.f, 0.f, 0.f, 0.f};

    for (int e = 0; e < NE; e++) {
        const int ce = cnts[e];
        if (ce == 0) continue;
        qjs[tid] = __uint_as_float((unsigned)Qbf[(((size_t)b * NE + e) * NN + j) * NH + tid] << 16);
        float bb[4];
#pragma unroll
        for (int nf = 0; nf < 4; nf++)
            bb[nf] = be2[e * NH + wave * 64 + nf * 16 + (lane & 15)];
        const unsigned short* Bt = We2t + (size_t)e * NH * NH;
        const unsigned short* Pb = Pbf + (size_t)(b * NE + e) * NN * NH;

        for (int base = 0; base < ce; base += 32) {
            __syncthreads();   // prev tile's readers done + qjs visible
            {   // ---- stage 32 rows: relu(P_i + Q_j) -> bf16, swizzled; 8 thr/row ----
                const int r = tid >> 3, q = tid & 7;      // q: 32-col chunk
                if (base + r < ce) {
                    const int i = lists[e][base + r];
                    const unsigned short* Pr = Pb + (size_t)i * NH + q * 32;
                    const float* qr = &qjs[q * 32];
                    char* wb = At + r * 512;
                    const int swz = (r & 7) << 4;
#pragma unroll
                    for (int x = 0; x < 4; x++) {
                        const uint4 pv = *(const uint4*)(Pr + x * 8);
                        const float4 q0 = *(const float4*)(qr + x * 8);
                        const float4 q1 = *(const float4*)(qr + x * 8 + 4);
                        const float f0 = fmaxf(bflo(pv.x) + q0.x, 0.f);
                        const float f1 = fmaxf(bfhi(pv.x) + q0.y, 0.f);
                        const float f2 = fmaxf(bflo(pv.y) + q0.z, 0.f);
                        const float f3 = fmaxf(bfhi(pv.y) + q0.w, 0.f);
                        const float f4 = fmaxf(bflo(pv.z) + q1.x, 0.f);
                        const float f5 = fmaxf(bfhi(pv.z) + q1.y, 0.f);
                        const float f6 = fmaxf(bflo(pv.w) + q1.z, 0.f);
                        const float f7 = fmaxf(bfhi(pv.w) + q1.w, 0.f);
                        uint4 pk;
                        pk.x = pk2bf(f0, f1); pk.y = pk2bf(f2, f3);
                        pk.z = pk2bf(f4, f5); pk.w = pk2bf(f6, f7);
                        *(uint4*)(wb + ((q * 64 + x * 16) ^ swz)) = pk;
                    }
                }
                // unstaged rows: stale/garbage bf16 only contaminates acc rows that
                // the epilogue masks (row g >= ce) -- never added to rsum.
            }
            __syncthreads();
            // ---- MFMA: 2 x 16-row sub-tiles x (wave's 64 cols) ----
            f32x4_t acc[2][4];
            const f32x4_t z4 = {0.f, 0.f, 0.f, 0.f};
#pragma unroll
            for (int mf = 0; mf < 2; mf++)
#pragma unroll
                for (int nf = 0; nf < 4; nf++) acc[mf][nf] = z4;
#pragma unroll
            for (int kk = 0; kk < 8; kk++) {
                bf16x8_t af[2];
                const int koff = kk * 64 + (lane >> 4) * 16;
#pragma unroll
                for (int mf = 0; mf < 2; mf++) {
                    const int lr = mf * 16 + (lane & 15);
                    af[mf] = *(const bf16x8_t*)(At + ((lr * 512 + koff) ^ ((lr & 7) << 4)));
                }
#pragma unroll
                for (int nf = 0; nf < 4; nf++) {
                    const int n = wave * 64 + nf * 16 + (lane & 15);
                    const bf16x8_t bfr = *(const bf16x8_t*)(Bt + (size_t)n * NH + kk * 32 + (lane >> 4) * 8);
#pragma unroll
                    for (int mf = 0; mf < 2; mf++)
                        acc[mf][nf] = __builtin_amdgcn_mfma_f32_16x16x32_bf16(af[mf], bfr, acc[mf][nf], 0, 0, 0);
                }
            }
            // ---- epilogue: bias+relu+mask, accumulate column sums ----
#pragma unroll
            for (int mf = 0; mf < 2; mf++) {
#pragma unroll
                for (int r = 0; r < 4; r++) {
                    const int g = base + mf * 16 + ((lane >> 4) << 2) + r;
                    if (g < ce) {
#pragma unroll
                        for (int nf = 0; nf < 4; nf++)
                            rsum[nf] += fmaxf(acc[mf][nf][r] + bb[nf], 0.f);
                    }
                }
            }
        }
    }

    // ---- reduce column sums over the 4 row-groups ----
#pragma unroll
    for (int nf = 0; nf < 4; nf++) {
        float v = rsum[nf];
        v += __shfl_xor(v, 16, 64);
        v += __shfl_xor(v, 32, 64);
        rsum[nf] = v;
    }
    if ((lane >> 4) == 0) {
#pragma unroll
        for (int nf = 0; nf < 4; nf++)
            aggr[wave * 64 + nf * 16 + lane] = rsum[nf];
    }
    __syncthreads();

    // ---- decoder layer 1: [ns(64), aggr(256)] -> relu(.Wd1 + bd1)(256) ----
    {
        const int col = tid;
        float a0 = bd1[col];
        const float* W = Wd1t + (size_t)col * 320;
#pragma unroll 4
        for (int cb = 0; cb < 16; cb++) {
            const float4 w = *(const float4*)(W + cb * 4);
            const float4 x0 = *(const float4*)(&nsr[cb * 4]);
            a0 = fmaf(w.x, x0.x, fmaf(w.y, x0.y, fmaf(w.z, x0.z, fmaf(w.w, x0.w, a0))));
        }
#pragma unroll 4
        for (int cb = 0; cb < 64; cb++) {
            const float4 w = *(const float4*)(W + 64 + cb * 4);
            const float4 x0 = *(const float4*)(&aggr[cb * 4]);
            a0 = fmaf(w.x, x0.x, fmaf(w.y, x0.y, fmaf(w.z, x0.z, fmaf(w.w, x0.w, a0))));
        }
        o1s[col] = fmaxf(a0, 0.f);
    }
    __syncthreads();
    // ---- decoder layer 2: (256) -> relu(.Wd2 + bd2)(64) ----
    if (tid < NOUT) {
        float a2 = bd2[tid];
        const float* W2 = Wd2t + (size_t)tid * NH;
#pragma unroll 4
        for (int hb = 0; hb < 64; hb++) {
            const float4 w = *(const float4*)(W2 + hb * 4);
            const float4 x = *(const float4*)(&o1s[hb * 4]);
            a2 = fmaf(w.x, x.x, fmaf(w.y, x.y, fmaf(w.z, x.z, fmaf(w.w, x.w, a2))));
        }
        out[((size_t)b * NN + j) * NOUT + tid] = fmaxf(a2, 0.f);
    }
}

extern "C" void kernel_launch(void* const* d_in, const int* in_sizes, int n_in,
                              void* d_out, int out_size, void* d_ws, size_t ws_size,
                              hipStream_t stream)
{
    const float* ns    = (const float*)d_in[0];
    const float* edges = (const float*)d_in[1];
    const float* We1   = (const float*)d_in[2];
    const float* be1   = (const float*)d_in[3];
    const float* We2   = (const float*)d_in[4];
    const float* be2   = (const float*)d_in[5];
    const float* Wd1   = (const float*)d_in[6];
    const float* bd1   = (const float*)d_in[7];
    const float* Wd2   = (const float*)d_in[8];
    const float* bd2   = (const float*)d_in[9];
    float* outp = (float*)d_out;

    unsigned short* Pbf  = (unsigned short*)d_ws;
    unsigned short* Qbf  = Pbf + (size_t)NB * NE * NN * NH;
    unsigned short* We2t = Qbf + (size_t)NB * NE * NN * NH;
    float* Wd1t = (float*)(We2t + (size_t)NE * NH * NH);
    float* Wd2t = Wd1t + 256 * 320;

    hipLaunchKernelGGL(prep_pq_kernel, dim3(480), dim3(256), 0, stream,
                       We2, Wd1, Wd2, ns, We1, be1, We2t, Wd1t, Wd2t, Pbf, Qbf);
    hipLaunchKernelGGL(edge_kernel, dim3(NB * NN), dim3(256), 0, stream,
                       ns, edges, Pbf, Qbf, We2t, be2, Wd1t, bd1, Wd2t, bd2, outp);
}